// Round 18
// baseline (4058.034 us; speedup 1.0000x reference)
//
#include <hip/hip_runtime.h>
#include <hip/hip_bf16.h>
#include <cstdint>
#include <cstddef>

#define BB 4
#define TT 2048
#define DD 512
#define NEG_INF (-3.402823466e+38f)
#define POS_INF (3.402823466e+38f)

typedef __attribute__((ext_vector_type(8))) short bf16x8;
typedef __attribute__((ext_vector_type(8))) unsigned short ushort8;
typedef __attribute__((ext_vector_type(4))) float f32x4;

__device__ __forceinline__ float sigmoidf_(float x){ return 1.0f/(1.0f+expf(-x)); }

// monotonic float<->uint map (no NaNs in sim values)
__device__ __forceinline__ unsigned int fwd_map(float f){
  unsigned int b = __float_as_uint(f);
  return b ^ ((b & 0x80000000u) ? 0xFFFFFFFFu : 0x80000000u);
}
__device__ __forceinline__ float inv_map(unsigned int u){
  unsigned int b = (u & 0x80000000u) ? (u ^ 0x80000000u) : ~u;
  return __uint_as_float(b);
}

__device__ __forceinline__ unsigned long long shfl_xor64(unsigned long long x, int off){
  unsigned int hi = __shfl_xor((unsigned int)(x >> 32), off);
  unsigned int lo = __shfl_xor((unsigned int)x, off);
  return ((unsigned long long)hi << 32) | lo;
}

// sort 64 keys descending across a wave; returns lane-th largest
__device__ __forceinline__ unsigned long long bitonic64_desc(unsigned long long key, int lane){
  unsigned long long nk = ~key;
  #pragma unroll
  for (int kk = 2; kk <= 64; kk <<= 1){
    #pragma unroll
    for (int j = kk >> 1; j > 0; j >>= 1){
      unsigned long long o = shfl_xor64(nk, j);
      bool keepMin = (((lane & kk) == 0) == ((lane & j) == 0));
      bool less = (nk < o);
      nk = (keepMin == less) ? nk : o;
    }
  }
  return ~nk;
}

// a, b sorted desc across lanes -> sorted desc top-64 of union
__device__ __forceinline__ unsigned long long merge_top64_desc(unsigned long long a, unsigned long long b, int lane){
  unsigned long long rev = shfl_xor64(b, 63);         // b reversed (asc)
  unsigned long long c = (a > rev) ? a : rev;          // bitonic, contains top-64
  #pragma unroll
  for (int j = 32; j > 0; j >>= 1){
    unsigned long long o = shfl_xor64(c, j);
    bool upper = (lane & j) != 0;
    c = upper ? ((c < o) ? c : o) : ((c > o) ? c : o);
  }
  return c;
}

// complete exact scan of a row: returns lane-th of sorted-desc top-64 keys
// FLIP=false: key = (fwd(val)<<32)|~s  (val desc, idx asc)
// FLIP=true : key = ~((fwd(val)<<32)|s) (transformed so desc == val asc, idx asc)
template<bool FLIP>
__device__ unsigned long long complete_top64(const float* __restrict__ hb, const float* __restrict__ rnb,
                                             const float* __restrict__ hq, float rt, int t, int lane){
  unsigned long long run = 0ull;
  for (int seg = 0; seg < t; seg += 64){
    int s = seg + lane;
    unsigned long long key = 0ull;
    if (s < t){
      const float* hc = hb + (size_t)s*DD;
      float pp = 0.f;
      #pragma unroll 4
      for (int i = 0; i < DD; i += 4){
        float4 qv = *(const float4*)&hq[i];
        float4 cv = *(const float4*)&hc[i];
        pp += qv.x*cv.x + qv.y*cv.y + qv.z*cv.z + qv.w*cv.w;
      }
      float ex = pp * rt * rnb[s];
      if (!FLIP) key = (((unsigned long long)fwd_map(ex)) << 32) | (unsigned int)(~s);
      else       key = ~((((unsigned long long)fwd_map(ex)) << 32) | (unsigned int)s);
    }
    key = bitonic64_desc(key, lane);
    run = merge_top64_desc(run, key, lane);
  }
  return run;
}

// ---------------- rnorm + RNE bf16 of xn ----------------
__global__ __launch_bounds__(64) void k_normsplit(const float* __restrict__ h, float* __restrict__ rnorm,
                                                  unsigned short* __restrict__ Xh){
  int row = blockIdx.x;
  const float* hr = h + (size_t)row*DD;
  int lane = threadIdx.x;
  float4 v0 = *(const float4*)&hr[lane*4];
  float4 v1 = *(const float4*)&hr[lane*4 + 256];
  float ss = v0.x*v0.x+v0.y*v0.y+v0.z*v0.z+v0.w*v0.w
           + v1.x*v1.x+v1.y*v1.y+v1.z*v1.z+v1.w*v1.w;
  #pragma unroll
  for (int off=32; off; off>>=1) ss += __shfl_xor(ss, off);
  float rn = 1.0f / fmaxf(sqrtf(ss), 1e-12f);
  if (lane==0) rnorm[row] = rn;

  float xs[8] = {v0.x,v0.y,v0.z,v0.w,v1.x,v1.y,v1.z,v1.w};
  unsigned short hv[8];
  #pragma unroll
  for (int q=0;q<8;q++){
    float xn = xs[q]*rn;
    unsigned int u = __float_as_uint(xn);
    unsigned int r = (u + 0x7FFFu + ((u >> 16) & 1u)) >> 16;   // RNE to bf16
    hv[q] = (unsigned short)r;
  }
  ushort4 h0 = {hv[0],hv[1],hv[2],hv[3]}, h1 = {hv[4],hv[5],hv[6],hv[7]};
  *(ushort4*)&Xh[(size_t)row*DD + lane*4]       = h0;
  *(ushort4*)&Xh[(size_t)row*DD + lane*4 + 256] = h1;
}

// async global->LDS, 16 bytes per lane
__device__ __forceinline__ void gl_lds16(const unsigned short* g, short* l){
  __builtin_amdgcn_global_load_lds(
    (const __attribute__((address_space(1))) unsigned int*)g,
    (__attribute__((address_space(3))) unsigned int*)l, 16, 0, 0);
}

// ---------------- approx sim via single-pass bf16 MFMA; writes key16 sidecar only ----------------
__global__ __launch_bounds__(512) void k_sim(const unsigned short* __restrict__ Xh,
                                             unsigned short* __restrict__ keys, int b0){
  int p = blockIdx.x;
  int jt = (int)((sqrtf(8.0f*(float)p + 1.0f) - 1.0f)*0.5f);
  while ((jt+1)*(jt+2)/2 <= p) jt++;
  while (jt*(jt+1)/2 > p) jt--;
  int is = p - jt*(jt+1)/2;

  int bl = blockIdx.y;
  size_t xoff = (size_t)(b0 + bl)*TT*DD;
  const unsigned short* XhB = Xh + xoff;
  unsigned short* keyb = keys + (size_t)bl*TT*TT;
  int t0 = jt*128, s0 = is*128;

  __shared__ __align__(16) short As[2][4096];
  __shared__ __align__(16) short Bs[2][4096];

  int tid = threadIdx.x, wave = tid>>6, lane = tid&63;
  int wr = wave>>2, wc = wave&3;

  int srow = tid>>2;
  int sc8  = (tid&3)*8;

  size_t offA = (size_t)(t0 + srow)*DD + sc8;
  size_t offB = (size_t)(s0 + srow)*DD + sc8;

  f32x4 acc[4][2];
  #pragma unroll
  for (int m=0;m<4;m++)
    #pragma unroll
    for (int n=0;n<2;n++) acc[m][n] = (f32x4){0.f,0.f,0.f,0.f};

  auto stage = [&](int s, int buf){
    int kcol = s*32;
    gl_lds16(XhB + offA + kcol, &As[buf][wave*512]);
    gl_lds16(XhB + offB + kcol, &Bs[buf][wave*512]);
  };

  stage(0, 0);
  __syncthreads();

  int arow = wr*64 + (lane&15);
  int brow = wc*32 + (lane&15);
  int kb = (lane>>4)*8;

  for (int s=0; s<16; ++s){
    int cur = s & 1;
    if (s < 15) stage(s+1, cur^1);
    bf16x8 af[4], bf[2];
    #pragma unroll
    for (int m=0;m<4;m++) af[m] = *(const bf16x8*)&As[cur][(arow + m*16)*32 + kb];
    #pragma unroll
    for (int n=0;n<2;n++) bf[n] = *(const bf16x8*)&Bs[cur][(brow + n*16)*32 + kb];
    #pragma unroll
    for (int m=0;m<4;m++)
      #pragma unroll
      for (int n=0;n<2;n++)
        acc[m][n] = __builtin_amdgcn_mfma_f32_16x16x32_bf16(af[m], bf[n], acc[m][n], 0, 0, 0);
    __syncthreads();
  }

  #pragma unroll
  for (int m=0;m<4;m++){
    int t = t0 + wr*64 + m*16 + (lane>>4)*4;
    #pragma unroll
    for (int n=0;n<2;n++){
      int sc = s0 + wc*32 + n*16 + (lane&15);
      unsigned short* kdst = keyb + (size_t)t*TT + sc;
      #pragma unroll
      for (int j=0;j<4;j++)
        kdst[(size_t)j*TT] = (unsigned short)(fwd_map(acc[m][n][j]) >> 16);
    }
  }
}

// ---------------- top-k: margin-collect from key16 sidecar + exact fp32 rescore ----------------
#define KLO(D,S) ( ((D) << 16)         | (0x7FFu - (unsigned int)(S)) )
#define KHI(D,S) ( ((D) & 0xFFFF0000u) | (0x7FFu - (unsigned int)(S)) )
#define INS32(KK) do{ unsigned int a=(KK); \
  if (a > kv3){ \
    if (a > kv0){ unsigned int q=kv0; kv0=a; a=q; } \
    if (a > kv1){ unsigned int q=kv1; kv1=a; a=q; } \
    if (a > kv2){ unsigned int q=kv2; kv2=a; a=q; } \
    kv3=a; } }while(0)
#define PROC8(W,S) { INS32(KLO((W).x,(S)));   INS32(KHI((W).x,(S)+1)); \
                     INS32(KLO((W).y,(S)+2)); INS32(KHI((W).y,(S)+3)); \
                     INS32(KLO((W).z,(S)+4)); INS32(KHI((W).z,(S)+5)); \
                     INS32(KLO((W).w,(S)+6)); INS32(KHI((W).w,(S)+7)); }

template<int ESIM, int ECON>
__global__ __launch_bounds__(256) void k_topk(const unsigned short* __restrict__ keys, int b0,
                                              const float* __restrict__ h, const float* __restrict__ rnorm,
                                              int* __restrict__ topidx, int* __restrict__ botidx,
                                              int* __restrict__ bcnt){
  constexpr int CAP = 128;
  constexpr float E2 = 0.02f;        // 2x certified |approx - exact| bound (0.008) with headroom
  __shared__ int s_cand[4][CAP];
  __shared__ int s_sel[4][16];

  int tid = threadIdx.x, lane = tid & 63, wid = tid >> 6;
  int lrow = blockIdx.x*4 + wid;
  int bl = lrow >> 11, t = lrow & (TT-1);
  int gb = b0 + bl;
  int grow = (gb << 11) | t;

  if (t <= ESIM){
    if (lane < t) topidx[(size_t)grow*16 + lane] = lane;
    if (lane == 0) bcnt[grow] = 0;
    return;
  }
  const unsigned short* krow = keys + (size_t)lrow*TT;
  const float* hb  = h + (size_t)gb*TT*DD;
  const float* rnb = rnorm + (size_t)gb*TT;
  const float* hq  = hb + (size_t)t*DD;
  float rt = rnb[t];

  int* scand = s_cand[wid];
  int* ssel  = s_sel[wid];
  unsigned long long below = (lane == 0) ? 0ull : ((~0ull) >> (64 - lane));

  // ---- A: sidecar sweep, per-lane top-4 packed (key16<<16 | 0x7FF - idx) ----
  unsigned int kv0=0, kv1=0, kv2=0, kv3=0;
  {
    int nd  = t >> 1;
    int nd4 = nd >> 2;
    const uint4* kr4 = (const uint4*)krow;
    uint4 w0, w1, w2, w3;
    bool g0 = (lane       < nd4);
    bool g1 = (lane +  64 < nd4);
    bool g2 = (lane + 128 < nd4);
    bool g3 = (lane + 192 < nd4);
    if (g0) w0 = kr4[lane];
    if (g1) w1 = kr4[lane + 64];
    if (g2) w2 = kr4[lane + 128];
    if (g3) w3 = kr4[lane + 192];
    if (g0) PROC8(w0, (lane)*8);
    if (g1) PROC8(w1, (lane+64)*8);
    if (g2) PROC8(w2, (lane+128)*8);
    if (g3) PROC8(w3, (lane+192)*8);
    for (int d = nd4*4 + lane; d < nd; d += 64){
      unsigned int w = ((const unsigned int*)krow)[d];
      int s = 2*d;
      INS32(KLO(w, s)); INS32(KHI(w, s+1));
    }
    if ((t & 1) && lane == 0){
      unsigned int u16 = krow[t-1];
      INS32((u16 << 16) | (0x7FFu - (unsigned int)(t-1)));
    }
  }
  int ck = (kv0?1:0) + (kv1?1:0) + (kv2?1:0) + (kv3?1:0);
  unsigned long long kb0=__ballot(ck&1), kb1=__ballot(ck&2), kb2=__ballot(ck&4);
  int kept = __popcll(kb0) + 2*__popcll(kb1) + 4*__popcll(kb2);

  bool complete = (kept < ESIM);
  int cnt = 0;
  if (!complete){
    // ---- B: binary search ESIM-th largest survivor (unique packed values) ----
    unsigned int v = 0;
    for (int bit = 31; bit >= 0; --bit){
      unsigned int test = v | (1u << bit);
      int c = (kv0>=test) + (kv1>=test) + (kv2>=test) + (kv3>=test);
      unsigned long long c0=__ballot(c&1), c1=__ballot(c&2), c2=__ballot(c&4);
      int cc = __popcll(c0) + 2*__popcll(c1) + 4*__popcll(c2);
      if (cc >= ESIM) v = test;
    }
    float L = inv_map((v >> 16) << 16);          // lower edge of observed k-th bucket <= true approx k-th
    unsigned int thc = fwd_map(L - E2) >> 16;    // margin threshold bucket

    // ---- C: collect all indices with key16 >= thc (ballot-prefix compaction) ----
    int nd = t >> 1;
    const unsigned int* kd = (const unsigned int*)krow;
    for (int d0 = 0; d0 < nd; d0 += 64){
      int d = d0 + lane;
      bool in = (d < nd);
      unsigned int w = in ? kd[d] : 0u;
      bool e0 = in && ((w & 0xFFFFu) >= thc);
      bool e1 = in && ((w >> 16)     >= thc);
      unsigned long long m0 = __ballot(e0), m1 = __ballot(e1);
      int n0 = __popcll(m0);
      int p0 = cnt + __popcll(m0 & below);
      int p1 = cnt + n0 + __popcll(m1 & below);
      if (e0 && p0 < CAP) scand[p0] = 2*d;
      if (e1 && p1 < CAP) scand[p1] = 2*d + 1;
      cnt += n0 + __popcll(m1);
    }
    if (t & 1){
      if (krow[t-1] >= thc){
        if (lane == 0 && cnt < CAP) scand[cnt] = t-1;
        cnt++;
      }
    }
    if (cnt > CAP || cnt < ESIM) complete = true;
  }

  if (!complete){
    // ---- D: exact fp32 rescore of candidates ----
    float4 q0 = *(const float4*)&hq[lane*4];
    float4 q1 = *(const float4*)&hq[lane*4 + 256];
    float ev0 = NEG_INF, ev1 = NEG_INF;
    for (int j = 0; j < cnt; ++j){
      int idx = scand[j];
      const float* hc = hb + (size_t)idx*DD;
      float4 c0 = *(const float4*)&hc[lane*4];
      float4 c1 = *(const float4*)&hc[lane*4 + 256];
      float pp = q0.x*c0.x+q0.y*c0.y+q0.z*c0.z+q0.w*c0.w
               + q1.x*c1.x+q1.y*c1.y+q1.z*c1.z+q1.w*c1.w;
      #pragma unroll
      for (int off=32; off; off>>=1) pp += __shfl_xor(pp, off);
      float ex = pp * rt * rnb[idx];
      if (lane == (j & 63)){ if (j < 64) ev0 = ex; else ev1 = ex; }
    }
    unsigned long long k0 = 0ull, k1 = 0ull;
    if (lane < cnt)      k0 = (((unsigned long long)fwd_map(ev0)) << 32) | (unsigned int)(~scand[lane]);
    if (lane + 64 < cnt) k1 = (((unsigned long long)fwd_map(ev1)) << 32) | (unsigned int)(~scand[lane+64]);
    k0 = bitonic64_desc(k0, lane);
    if (cnt > 64){
      k1 = bitonic64_desc(k1, lane);
      k0 = merge_top64_desc(k0, k1, lane);
    }
    int idx_l = (int)(~(unsigned int)k0);
    if (lane < ESIM){
      ssel[lane] = idx_l;
      topidx[(size_t)grow*16 + lane] = idx_l;
    }
  } else {
    // ---- E: complete exact scan (top) ----
    unsigned long long rk = complete_top64<false>(hb, rnb, hq, rt, t, lane);
    int idx_l = (int)(~(unsigned int)rk);
    if (lane < ESIM){
      ssel[lane] = idx_l;
      topidx[(size_t)grow*16 + lane] = idx_l;
    }
  }

  // ---- bottoms: rows with t > TT-ECON only (<=7 per batch), complete exact scan ----
  int need = ECON - (TT - t);
  int cnt2 = 0;
  if (need > 0){
    unsigned long long rb = complete_top64<true>(hb, rnb, hq, rt, t, lane);
    unsigned long long real = ~rb;                 // sorted asc by (val, idx)
    int bidx = (int)(unsigned int)real;            // low 32 = index
    for (int k = 0; k < 64 && cnt2 < need; ++k){
      int bi = __shfl(bidx, k);
      bool mem = false;
      #pragma unroll
      for (int j = 0; j < ESIM; ++j) if (ssel[j] == bi) mem = true;
      if (!mem){
        if (lane == 0) botidx[(size_t)grow*8 + cnt2] = bi;
        cnt2++;
      }
    }
  }
  if (lane == 0) bcnt[grow] = cnt2;
}

// ---------------- aggregate + blend + gelu + momentum ----------------
__global__ __launch_bounds__(256) void k_agg(const float* __restrict__ hsrc, float* __restrict__ hdst,
                                             const int* __restrict__ topidx, const int* __restrict__ botidx,
                                             const int* __restrict__ bcnt,
                                             const float* __restrict__ gain, const float* __restrict__ bias,
                                             const float* __restrict__ log_mix, const float* __restrict__ log_alpha,
                                             const float* __restrict__ log_momentum, int r, int eff_sim){
  int row = blockIdx.x;
  int b = row >> 11; int t = row & (TT-1);
  int n_sim = min(eff_sim, t);
  int n_con = bcnt[row];
  float mix      = sigmoidf_(log_mix[r]);
  float alpha    = sigmoidf_(log_alpha[r]);
  float momentum = sigmoidf_(log_momentum[0]);
  const float* hb = hsrc + (size_t)b*TT*DD;

  __shared__ int sidx[16];
  __shared__ int scidx[8];
  if (threadIdx.x < 16) sidx[threadIdx.x]  = (threadIdx.x < n_sim) ? topidx[(size_t)row*16 + threadIdx.x] : 0;
  if (threadIdx.x < 8)  scidx[threadIdx.x] = (threadIdx.x < n_con) ? botidx[(size_t)row*8  + threadIdx.x] : 0;
  __syncthreads();

  #pragma unroll
  for (int e = threadIdx.x; e < DD; e += 256){
    float sp = 0.f;
    for (int j=0;j<n_sim;j++) sp += hb[(size_t)sidx[j]*DD + e];
    float sn = 0.f;
    for (int j=0;j<n_con;j++) sn += hb[(size_t)scidx[j]*DD + e];
    float mp = sp / (float)max(n_sim, 1);
    float mn = sn / (float)max(n_con, 1);
    float ctx = alpha*mp + (1.f-alpha)*mn;
    float hv = hsrc[(size_t)row*DD + e];
    float blended = mix*hv + (1.f-mix)*ctx;
    float u = blended*gain[e] + bias[e];
    float g = 0.5f*u*(1.0f + erff(u*0.7071067811865475f));
    hdst[(size_t)row*DD + e] = momentum*hv + (1.f-momentum)*g;
  }
}

// ---------------- out = (h - x) * scale ----------------
__global__ __launch_bounds__(256) void k_final(const float* __restrict__ hfin, const float* __restrict__ x,
                                               const float* __restrict__ log_scale, float* __restrict__ out, int n){
  float scale = log1pf(expf(log_scale[0])) + 0.01f;
  int i = blockIdx.x*256 + threadIdx.x;
  if (i < n) out[i] = (hfin[i] - x[i]) * scale;
}

extern "C" void kernel_launch(void* const* d_in, const int* in_sizes, int n_in,
                              void* d_out, int out_size, void* d_ws, size_t ws_size,
                              hipStream_t stream) {
  const float* x         = (const float*)d_in[0];
  const float* gain      = (const float*)d_in[1];
  const float* bias      = (const float*)d_in[2];
  const float* log_mix   = (const float*)d_in[3];
  const float* log_alpha = (const float*)d_in[4];
  const float* log_mom   = (const float*)d_in[5];
  const float* log_scale = (const float*)d_in[6];

  float* hA = (float*)d_out;
  char* ws = (char*)d_ws;
  size_t off = 0;
  auto alloc = [&](size_t bytes){ void* p = ws + off; off += (bytes + 255) & ~(size_t)255; return p; };

  float*          hB     = (float*)alloc((size_t)BB*TT*DD*4);
  float*          rnorm  = (float*)alloc((size_t)BB*TT*4);
  int*            topidx = (int*)  alloc((size_t)BB*TT*16*4);
  int*            botidx = (int*)  alloc((size_t)BB*TT*8*4);
  int*            bcnt   = (int*)  alloc((size_t)BB*TT*4);
  unsigned short* Xh     = (unsigned short*)alloc((size_t)BB*TT*DD*2);

  size_t rem = (ws_size > off) ? (ws_size - off) : 0;
  int cb = (int)(rem / ((size_t)TT*TT*2 + 512));
  if (cb < 1) cb = 1;
  if (cb > BB) cb = BB;
  unsigned short* keys = (unsigned short*)alloc((size_t)cb*TT*TT*2);

  const float* hsrc = x;
  float* hdst = hB;
  const int ks[3] = {4, 8, 16};

  for (int r = 0; r < 3; ++r){
    k_normsplit<<<BB*TT, 64, 0, stream>>>(hsrc, rnorm, Xh);
    for (int b0 = 0; b0 < BB; b0 += cb){
      int nb = (BB - b0 < cb) ? (BB - b0) : cb;
      dim3 g(136, nb);
      k_sim<<<g, 512, 0, stream>>>(Xh, keys, b0);
      if (r == 0)      k_topk<4,2><<<nb*TT/4, 256, 0, stream>>>(keys, b0, hsrc, rnorm, topidx, botidx, bcnt);
      else if (r == 1) k_topk<8,4><<<nb*TT/4, 256, 0, stream>>>(keys, b0, hsrc, rnorm, topidx, botidx, bcnt);
      else             k_topk<16,8><<<nb*TT/4, 256, 0, stream>>>(keys, b0, hsrc, rnorm, topidx, botidx, bcnt);
    }
    k_agg<<<BB*TT, 256, 0, stream>>>(hsrc, hdst, topidx, botidx, bcnt,
                                     gain + (size_t)r*DD, bias + (size_t)r*DD,
                                     log_mix, log_alpha, log_mom, r, ks[r]);
    if (r == 0){ hsrc = hB; hdst = hA; }
    else if (r == 1){ hsrc = hA; hdst = hB; }
  }
  k_final<<<(BB*TT*DD)/256, 256, 0, stream>>>(hB, x, log_scale, (float*)d_out, BB*TT*DD);
}

// Round 19
// 741.626 us; speedup vs baseline: 5.4718x; 5.4718x over previous
//
#include <hip/hip_runtime.h>
#include <hip/hip_bf16.h>
#include <cstdint>
#include <cstddef>

#define BB 4
#define TT 2048
#define DD 512
#define NEG_INF (-3.402823466e+38f)
#define POS_INF (3.402823466e+38f)

typedef __attribute__((ext_vector_type(8))) short bf16x8;
typedef __attribute__((ext_vector_type(8))) unsigned short ushort8;
typedef __attribute__((ext_vector_type(4))) float f32x4;

__device__ __forceinline__ float sigmoidf_(float x){ return 1.0f/(1.0f+expf(-x)); }

__device__ __forceinline__ unsigned short f2bf(float x){
  __hip_bfloat16 b = __float2bfloat16(x);
  return *reinterpret_cast<unsigned short*>(&b);
}

// monotonic float<->uint map (no NaNs in sim values)
__device__ __forceinline__ unsigned int fwd_map(float f){
  unsigned int b = __float_as_uint(f);
  return b ^ ((b & 0x80000000u) ? 0xFFFFFFFFu : 0x80000000u);
}
__device__ __forceinline__ float inv_map(unsigned int u){
  unsigned int b = (u & 0x80000000u) ? (u ^ 0x80000000u) : ~u;
  return __uint_as_float(b);
}

__device__ __forceinline__ unsigned long long shfl_xor64(unsigned long long x, int off){
  unsigned int hi = __shfl_xor((unsigned int)(x >> 32), off);
  unsigned int lo = __shfl_xor((unsigned int)x, off);
  return ((unsigned long long)hi << 32) | lo;
}

// ---------------- rnorm + bf16 hi/lo split of xn ----------------
__global__ __launch_bounds__(64) void k_normsplit(const float* __restrict__ h, float* __restrict__ rnorm,
                                                  unsigned short* __restrict__ Xh, unsigned short* __restrict__ Xl){
  int row = blockIdx.x;
  const float* hr = h + (size_t)row*DD;
  int lane = threadIdx.x;
  float4 v0 = *(const float4*)&hr[lane*4];
  float4 v1 = *(const float4*)&hr[lane*4 + 256];
  float ss = v0.x*v0.x+v0.y*v0.y+v0.z*v0.z+v0.w*v0.w
           + v1.x*v1.x+v1.y*v1.y+v1.z*v1.z+v1.w*v1.w;
  #pragma unroll
  for (int off=32; off; off>>=1) ss += __shfl_xor(ss, off);
  float rn = 1.0f / fmaxf(sqrtf(ss), 1e-12f);
  if (lane==0) rnorm[row] = rn;

  float xs[8] = {v0.x,v0.y,v0.z,v0.w,v1.x,v1.y,v1.z,v1.w};
  unsigned short hb[8], lb[8];
  #pragma unroll
  for (int q=0;q<8;q++){
    float xn = xs[q]*rn;
    unsigned short hh = f2bf(xn);
    __hip_bfloat16 bh = *reinterpret_cast<__hip_bfloat16*>(&hh);
    float rem = xn - __bfloat162float(bh);
    hb[q] = hh; lb[q] = f2bf(rem);
  }
  ushort4 h0 = {hb[0],hb[1],hb[2],hb[3]}, h1 = {hb[4],hb[5],hb[6],hb[7]};
  ushort4 l0 = {lb[0],lb[1],lb[2],lb[3]}, l1 = {lb[4],lb[5],lb[6],lb[7]};
  *(ushort4*)&Xh[(size_t)row*DD + lane*4]       = h0;
  *(ushort4*)&Xh[(size_t)row*DD + lane*4 + 256] = h1;
  *(ushort4*)&Xl[(size_t)row*DD + lane*4]       = l0;
  *(ushort4*)&Xl[(size_t)row*DD + lane*4 + 256] = l1;
}

// ---------------- sim via MFMA bf16 3-pass split, 128x128 tile ----------------
__global__ __launch_bounds__(256) void k_sim(const unsigned short* __restrict__ Xh,
                                             const unsigned short* __restrict__ Xl,
                                             float* __restrict__ sim, int b0){
  int p = blockIdx.x;
  int jt = (int)((sqrtf(8.0f*(float)p + 1.0f) - 1.0f)*0.5f);
  while ((jt+1)*(jt+2)/2 <= p) jt++;
  while (jt*(jt+1)/2 > p) jt--;
  int is = p - jt*(jt+1)/2;

  int bl = blockIdx.y;
  size_t xoff = (size_t)(b0 + bl)*TT*DD;
  const unsigned short* XhB = Xh + xoff;
  const unsigned short* XlB = Xl + xoff;
  float* simb = sim + (size_t)bl*TT*TT;
  int t0 = jt*128, s0 = is*128;

  __shared__ __align__(16) short As[128*32];
  __shared__ __align__(16) short Bs[128*32];

  int tid = threadIdx.x, wave = tid>>6, lane = tid&63;
  int wr = wave>>1, wc = wave&1;

  int srow = tid>>2;
  int sc8  = (tid&3)*8;

  f32x4 acc[4][4];
  #pragma unroll
  for (int m=0;m<4;m++)
    #pragma unroll
    for (int n=0;n<4;n++) acc[m][n] = (f32x4){0.f,0.f,0.f,0.f};

  ushort8 ra0, ra1, rb0, rb1;
  auto gload = [&](int s){
    int pass = s>>4; int kcol = (s&15)*32;
    const unsigned short* sA = (pass<2) ? XhB : XlB;
    const unsigned short* sB = (pass!=1) ? XhB : XlB;
    ra0 = *(const ushort8*)&sA[(size_t)(t0+srow)*DD + kcol + sc8];
    ra1 = *(const ushort8*)&sA[(size_t)(t0+srow+64)*DD + kcol + sc8];
    rb0 = *(const ushort8*)&sB[(size_t)(s0+srow)*DD + kcol + sc8];
    rb1 = *(const ushort8*)&sB[(size_t)(s0+srow+64)*DD + kcol + sc8];
  };

  gload(0);
  for (int s=0; s<48; ++s){
    __syncthreads();
    *(ushort8*)&As[srow*32 + sc8]      = ra0;
    *(ushort8*)&As[(srow+64)*32 + sc8] = ra1;
    *(ushort8*)&Bs[srow*32 + sc8]      = rb0;
    *(ushort8*)&Bs[(srow+64)*32 + sc8] = rb1;
    __syncthreads();
    if (s < 47) gload(s+1);

    int arow = wr*64 + (lane&15);
    int brow = wc*64 + (lane&15);
    int kb = (lane>>4)*8;
    bf16x8 af[4], bf[4];
    #pragma unroll
    for (int m=0;m<4;m++) af[m] = *(const bf16x8*)&As[(arow + m*16)*32 + kb];
    #pragma unroll
    for (int n=0;n<4;n++) bf[n] = *(const bf16x8*)&Bs[(brow + n*16)*32 + kb];
    #pragma unroll
    for (int m=0;m<4;m++)
      #pragma unroll
      for (int n=0;n<4;n++)
        acc[m][n] = __builtin_amdgcn_mfma_f32_16x16x32_bf16(af[m], bf[n], acc[m][n], 0, 0, 0);
  }

  #pragma unroll
  for (int m=0;m<4;m++){
    int t = t0 + wr*64 + m*16 + (lane>>4)*4;
    #pragma unroll
    for (int n=0;n<4;n++){
      int sc = s0 + wc*64 + n*16 + (lane&15);
      float* dst = simb + (size_t)t*TT + sc;
      #pragma unroll
      for (int j=0;j<4;j++) dst[(size_t)j*TT] = acc[m][n][j];
    }
  }
}

// ---------------- top-k helpers ----------------
#define BMASK 0xFFFFFF00u
#define MK64(F,S) ((((unsigned long long)fwd_map(F)) << 32) | (unsigned int)(~(S)))
#define INS4(K0,K1v,K2,K3,KK) do{ unsigned long long a_=(KK); \
  if (a_ > K3){ \
    if (a_ > K0){ unsigned long long q_=K0; K0=a_; a_=q_; } \
    if (a_ > K1v){ unsigned long long q_=K1v; K1v=a_; a_=q_; } \
    if (a_ > K2){ unsigned long long q_=K2; K2=a_; a_=q_; } \
    K3=a_; } }while(0)

#define SWROW(BASE, PTR, TX, Q0,Q1,Q2,Q3) do{ \
  float4 f0_=*(const float4*)&(PTR)[(BASE)],     f1_=*(const float4*)&(PTR)[(BASE)+256], \
         f2_=*(const float4*)&(PTR)[(BASE)+512], f3_=*(const float4*)&(PTR)[(BASE)+768]; \
  int sb_=(BASE); \
  if(sb_    <(TX)) INS4(Q0,Q1,Q2,Q3, MK64(f0_.x,sb_));     \
  if(sb_+1  <(TX)) INS4(Q0,Q1,Q2,Q3, MK64(f0_.y,sb_+1));   \
  if(sb_+2  <(TX)) INS4(Q0,Q1,Q2,Q3, MK64(f0_.z,sb_+2));   \
  if(sb_+3  <(TX)) INS4(Q0,Q1,Q2,Q3, MK64(f0_.w,sb_+3));   \
  if(sb_+256<(TX)) INS4(Q0,Q1,Q2,Q3, MK64(f1_.x,sb_+256)); \
  if(sb_+257<(TX)) INS4(Q0,Q1,Q2,Q3, MK64(f1_.y,sb_+257)); \
  if(sb_+258<(TX)) INS4(Q0,Q1,Q2,Q3, MK64(f1_.z,sb_+258)); \
  if(sb_+259<(TX)) INS4(Q0,Q1,Q2,Q3, MK64(f1_.w,sb_+259)); \
  if(sb_+512<(TX)) INS4(Q0,Q1,Q2,Q3, MK64(f2_.x,sb_+512)); \
  if(sb_+513<(TX)) INS4(Q0,Q1,Q2,Q3, MK64(f2_.y,sb_+513)); \
  if(sb_+514<(TX)) INS4(Q0,Q1,Q2,Q3, MK64(f2_.z,sb_+514)); \
  if(sb_+515<(TX)) INS4(Q0,Q1,Q2,Q3, MK64(f2_.w,sb_+515)); \
  if(sb_+768<(TX)) INS4(Q0,Q1,Q2,Q3, MK64(f3_.x,sb_+768)); \
  if(sb_+769<(TX)) INS4(Q0,Q1,Q2,Q3, MK64(f3_.y,sb_+769)); \
  if(sb_+770<(TX)) INS4(Q0,Q1,Q2,Q3, MK64(f3_.z,sb_+770)); \
  if(sb_+771<(TX)) INS4(Q0,Q1,Q2,Q3, MK64(f3_.w,sb_+771)); \
}while(0)

// 3-pass radix: exact 24-bit bucket of the k1-th largest key (key = fwd_map ^ flip); wave-level
__device__ __attribute__((noinline)) unsigned int radix24(const float* __restrict__ srow, int t, int k1,
                                                          unsigned int flip, int* sh, int lane){
  #pragma unroll
  for (int i=0;i<4;i++) sh[lane + i*64] = 0;
  int t4 = t & ~3;
  for (int s4 = lane*4; s4 < t4; s4 += 256){
    float4 f = *(const float4*)&srow[s4];
    unsigned int u0=fwd_map(f.x)^flip, u1=fwd_map(f.y)^flip, u2=fwd_map(f.z)^flip, u3=fwd_map(f.w)^flip;
    atomicAdd(&sh[u0>>24],1); atomicAdd(&sh[u1>>24],1);
    atomicAdd(&sh[u2>>24],1); atomicAdd(&sh[u3>>24],1);
  }
  for (int s = t4 + lane; s < t; s += 64){
    unsigned int u = fwd_map(srow[s])^flip;
    atomicAdd(&sh[u>>24],1);
  }
  unsigned int pfx = 0u; int kp = k1;
  #pragma unroll
  for (int pass = 0; pass < 3; ++pass){
    int shift = 24 - 8*pass;
    int m4 = sh[4*lane] + sh[4*lane+1] + sh[4*lane+2] + sh[4*lane+3];
    int x = __shfl(m4, 63-lane);
    #pragma unroll
    for (int off = 1; off < 64; off <<= 1){
      int v = __shfl_up(x, off);
      if (lane >= off) x += v;
    }
    int T = __shfl(x, 63-lane);
    int G = T - m4;
    bool hit = (G < kp) && (kp <= T);
    unsigned int npfx = 0u; int nkp = 0;
    if (hit){
      int c = G; int D = 4*lane;
      #pragma unroll
      for (int i = 3; i >= 0; --i){
        int hc = sh[4*lane + i];
        if (kp <= c + hc){ D = 4*lane + i; break; }
        c += hc;
      }
      npfx = pfx | ((unsigned int)D << shift);
      nkp = kp - c;
    }
    unsigned long long hm = __ballot(hit);
    int src = __ffsll(hm) - 1;
    pfx = __shfl(npfx, src);
    kp  = __shfl(nkp, src);
    if (pass == 2) break;

    int nshift = shift - 8;
    unsigned int keep = 0xFFFFFFFFu << shift;
    #pragma unroll
    for (int i=0;i<4;i++) sh[lane + i*64] = 0;
    for (int s4 = lane*4; s4 < t4; s4 += 256){
      float4 f = *(const float4*)&srow[s4];
      unsigned int u0=fwd_map(f.x)^flip, u1=fwd_map(f.y)^flip, u2=fwd_map(f.z)^flip, u3=fwd_map(f.w)^flip;
      if (((u0 ^ pfx) & keep) == 0) atomicAdd(&sh[(u0>>nshift)&255],1);
      if (((u1 ^ pfx) & keep) == 0) atomicAdd(&sh[(u1>>nshift)&255],1);
      if (((u2 ^ pfx) & keep) == 0) atomicAdd(&sh[(u2>>nshift)&255],1);
      if (((u3 ^ pfx) & keep) == 0) atomicAdd(&sh[(u3>>nshift)&255],1);
    }
    for (int s = t4 + lane; s < t; s += 64){
      unsigned int u = fwd_map(srow[s])^flip;
      if (((u ^ pfx) & keep) == 0) atomicAdd(&sh[(u>>nshift)&255],1);
    }
  }
  return pfx;   // low 8 bits zero
}

// ---------------- top-k: 4 rows per wave, 16 loads in flight; cert + radix fallback ----------------
template<int ESIM, int ECON>
__global__ __launch_bounds__(256) void k_topk(const float* __restrict__ sim, int b0,
                                              const float* __restrict__ h, const float* __restrict__ rnorm,
                                              int* __restrict__ topidx, int* __restrict__ botidx,
                                              int* __restrict__ bcnt, int rquarter){
  constexpr int K1  = ESIM + 8;
  constexpr int K1B = ESIM + ECON + 8;
  constexpr int CANDCAP = 40;
  constexpr int EQCAP = 44;
  constexpr float TAU = 5e-5f;
  __shared__ int s_hist[4][256];
  __shared__ int s_cand[4][CANDCAP];
  __shared__ int s_eq[4][EQCAP];
  __shared__ int s_sel[4][ESIM];
  __shared__ int s_bot[4][16];
  __shared__ int s_cnt[4][2];

  int tid = threadIdx.x, lane = tid & 63, wid = tid >> 6;
  int W = blockIdx.x*4 + wid;

  int lr0 = W, lr1 = W + rquarter, lr2 = W + 2*rquarter, lr3 = W + 3*rquarter;
  int tA = lr0 & (TT-1), tB = lr1 & (TT-1), tC = lr2 & (TT-1), tD = lr3 & (TT-1);
  const float* sA_ = sim + (size_t)lr0*TT;
  const float* sB_ = sim + (size_t)lr1*TT;
  const float* sC_ = sim + (size_t)lr2*TT;
  const float* sD_ = sim + (size_t)lr3*TT;

  int* sh    = s_hist[wid];
  int* scand = s_cand[wid];
  int* seq   = s_eq[wid];
  int* ssel  = s_sel[wid];
  int* sbot  = s_bot[wid];

  // ========== sweep: 4 rows, up to 16 float4 loads in flight per iteration ==========
  unsigned long long kA0=0,kA1=0,kA2=0,kA3=0, kB0=0,kB1=0,kB2=0,kB3=0,
                     kC0=0,kC1=0,kC2=0,kC3=0, kD0=0,kD1=0,kD2=0,kD3=0;
  {
    int base0 = lane*4;                     // covers [0,1024)
    if (tA > ESIM) SWROW(base0, sA_, tA, kA0,kA1,kA2,kA3);
    if (tB > ESIM) SWROW(base0, sB_, tB, kB0,kB1,kB2,kB3);
    if (tC > ESIM) SWROW(base0, sC_, tC, kC0,kC1,kC2,kC3);
    if (tD > ESIM) SWROW(base0, sD_, tD, kD0,kD1,kD2,kD3);
    int base1 = 1024 + lane*4;              // covers [1024,2048), max addr 2044+3=2047
    if (tA > 1024) SWROW(base1, sA_, tA, kA0,kA1,kA2,kA3);
    if (tB > 1024) SWROW(base1, sB_, tB, kB0,kB1,kB2,kB3);
    if (tC > 1024) SWROW(base1, sC_, tC, kC0,kC1,kC2,kC3);
    if (tD > 1024) SWROW(base1, sD_, tD, kD0,kD1,kD2,kD3);
  }

  // ========== per-row finish (R11-verbatim logic) ==========
  #pragma unroll
  for (int q = 0; q < 4; ++q){
    unsigned long long w0,w1,w2,w3;
    const float* srow; int t, lrow;
    if (q==0){ w0=kA0;w1=kA1;w2=kA2;w3=kA3; srow=sA_; t=tA; lrow=lr0; }
    else if (q==1){ w0=kB0;w1=kB1;w2=kB2;w3=kB3; srow=sB_; t=tB; lrow=lr1; }
    else if (q==2){ w0=kC0;w1=kC1;w2=kC2;w3=kC3; srow=sC_; t=tC; lrow=lr2; }
    else { w0=kD0;w1=kD1;w2=kD2;w3=kD3; srow=sD_; t=tD; lrow=lr3; }
    int gb = b0 + (lrow >> 11);
    int grow = (gb << 11) | t;
    const float* hb  = h + (size_t)gb*TT*DD;
    const float* rnb = rnorm + (size_t)gb*TT;
    int t4 = t & ~3;

    if (t <= ESIM){
      if (lane < t) topidx[(size_t)grow*16 + lane] = lane;
      if (lane == 0) bcnt[grow] = 0;
      continue;
    }

    // certificate: w3 bounds (strictly above) every key this lane ever discarded
    unsigned long long cert = w3;
    #pragma unroll
    for (int off=32; off; off>>=1){
      unsigned long long oc = shfl_xor64(cert, off);
      if (oc > cert) cert = oc;
    }

    int myidx = 0x7fffffff;
    float vA = 0.f, vB = 0.f;
    unsigned long long keyLast = 0ull;
    #pragma unroll
    for (int k = 0; k <= ESIM; ++k){
      unsigned long long bk = w0;
      #pragma unroll
      for (int off=32; off; off>>=1){
        unsigned long long ok = shfl_xor64(bk, off);
        if (ok > bk) bk = ok;
      }
      if (w0 == bk){ w0=w1; w1=w2; w2=w3; w3=0ull; }
      if (lane == k) myidx = (int)(~(unsigned int)bk);
      if (k == ESIM-1) vA = inv_map((unsigned int)(bk >> 32));
      if (k == ESIM){ vB = inv_map((unsigned int)(bk >> 32)); keyLast = bk; }
    }

    bool fb = (cert > keyLast) || (vA - vB < TAU);
    if (!fb){
      if (lane < ESIM){
        ssel[lane] = myidx;
        topidx[(size_t)grow*16 + lane] = myidx;
      }
    } else {
      // ===== FALLBACK: radix24 + collect + extract + gap/rescore =====
      int k1 = min(t, K1);
      unsigned int thr = radix24(srow, t, k1, 0u, sh, lane);

      if (lane == 0){ s_cnt[wid][0] = 0; s_cnt[wid][1] = 0; }
      for (int s4 = lane*4; s4 < t4; s4 += 256){
        float4 f = *(const float4*)&srow[s4];
        unsigned int uu[4] = {fwd_map(f.x), fwd_map(f.y), fwd_map(f.z), fwd_map(f.w)};
        #pragma unroll
        for (int qq=0;qq<4;qq++){
          unsigned int b24 = uu[qq] & BMASK;
          if (b24 > thr){ int p = atomicAdd(&s_cnt[wid][0],1); if (p < CANDCAP) scand[p] = s4+qq; }
          else if (b24 == thr){ int p = atomicAdd(&s_cnt[wid][1],1); if (p < EQCAP) seq[p] = s4+qq; }
        }
      }
      for (int s = t4 + lane; s < t; s += 64){
        unsigned int b24 = fwd_map(srow[s]) & BMASK;
        if (b24 > thr){ int p = atomicAdd(&s_cnt[wid][0],1); if (p < CANDCAP) scand[p] = s; }
        else if (b24 == thr){ int p = atomicAdd(&s_cnt[wid][1],1); if (p < EQCAP) seq[p] = s; }
      }
      int c_gt = min(s_cnt[wid][0], CANDCAP);
      int c_eq = min(s_cnt[wid][1], EQCAP);
      int ncand = min(c_gt + c_eq, 64);

      unsigned int myu = 0u; int myi = 0x7fffffff;
      if (lane < ncand){
        myi = (lane < c_gt) ? scand[lane] : seq[lane - c_gt];
        myu = fwd_map(srow[myi]);
      }

      float fvA = 0.f, fvB = 0.f;
      {
        unsigned int cu = myu; int ci = myi;
        #pragma unroll
        for (int k = 0; k <= ESIM; ++k){
          unsigned int bu = cu; int bi = ci;
          #pragma unroll
          for (int off=32; off; off>>=1){
            unsigned int ou = __shfl_xor(bu, off); int oi = __shfl_xor(bi, off);
            if (ou > bu || (ou == bu && oi < bi)){ bu = ou; bi = oi; }
          }
          if (k < ESIM && lane == 0) ssel[k] = bi;
          if (k == ESIM-1) fvA = inv_map(bu);
          if (k == ESIM)   fvB = inv_map(bu);
          if (ci == bi){ cu = 0u; ci = 0x7fffffff; }
        }
      }

      bool resc = (fvA - fvB < TAU);
      if (resc){
        const float* hq = hb + (size_t)t*DD;
        float rt = rnb[t];
        float4 q0 = *(const float4*)&hq[lane*4];
        float4 q1 = *(const float4*)&hq[lane*4 + 256];
        float ev = NEG_INF;
        for (int j = 0; j < ncand; ++j){
          int idx = (j < c_gt) ? scand[j] : seq[j - c_gt];
          const float* hc = hb + (size_t)idx*DD;
          float4 c0 = *(const float4*)&hc[lane*4];
          float4 c1 = *(const float4*)&hc[lane*4 + 256];
          float pp = q0.x*c0.x+q0.y*c0.y+q0.z*c0.z+q0.w*c0.w
                   + q1.x*c1.x+q1.y*c1.y+q1.z*c1.z+q1.w*c1.w;
          #pragma unroll
          for (int off=32; off; off>>=1) pp += __shfl_xor(pp, off);
          float ex = pp * rt * rnb[idx];
          if (lane == j) ev = ex;
        }
        float rv = (lane < ncand) ? ev : NEG_INF;
        int   ri = myi;
        #pragma unroll
        for (int k = 0; k < ESIM; ++k){
          float bv = rv; int bi = ri;
          #pragma unroll
          for (int off=32; off; off>>=1){
            float ov = __shfl_xor(bv, off); int oi = __shfl_xor(bi, off);
            if (ov > bv || (ov == bv && oi < bi)){ bv = ov; bi = oi; }
          }
          if (lane == 0) ssel[k] = bi;
          if (ri == bi) rv = NEG_INF;
        }
      }
      if (lane < ESIM) topidx[(size_t)grow*16 + lane] = ssel[lane];
    }

    // ---------- BOTTOM path (rows with t > TT-ECON only, <=7 per batch) ----------
    int need = ECON - (TT - t);
    int cnt2 = 0;
    if (need > 0){
      constexpr unsigned int FLIP = 0xFFFFFFFFu;
      int k1b = min(t, K1B);
      unsigned int thrb = radix24(srow, t, k1b, FLIP, sh, lane);

      if (lane == 0){ s_cnt[wid][0] = 0; s_cnt[wid][1] = 0; }
      for (int s4 = lane*4; s4 < t4; s4 += 256){
        float4 f = *(const float4*)&srow[s4];
        unsigned int uu[4] = {fwd_map(f.x)^FLIP, fwd_map(f.y)^FLIP, fwd_map(f.z)^FLIP, fwd_map(f.w)^FLIP};
        #pragma unroll
        for (int qq=0;qq<4;qq++){
          unsigned int b24 = uu[qq] & BMASK;
          if (b24 > thrb){ int p = atomicAdd(&s_cnt[wid][0],1); if (p < CANDCAP) scand[p] = s4+qq; }
          else if (b24 == thrb){ int p = atomicAdd(&s_cnt[wid][1],1); if (p < EQCAP) seq[p] = s4+qq; }
        }
      }
      for (int s = t4 + lane; s < t; s += 64){
        unsigned int u = fwd_map(srow[s])^FLIP;
        unsigned int b24 = u & BMASK;
        if (b24 > thrb){ int p = atomicAdd(&s_cnt[wid][0],1); if (p < CANDCAP) scand[p] = s; }
        else if (b24 == thrb){ int p = atomicAdd(&s_cnt[wid][1],1); if (p < EQCAP) seq[p] = s; }
      }
      int bc_gt = min(s_cnt[wid][0], CANDCAP);
      int bc_eq = min(s_cnt[wid][1], EQCAP);
      int ncb = min(bc_gt + bc_eq, 64);

      unsigned int mu = 0u; int mi = 0x7fffffff;
      if (lane < ncb){
        mi = (lane < bc_gt) ? scand[lane] : seq[lane - bc_gt];
        mu = fwd_map(srow[mi]) ^ FLIP;
      }
      float wA = 0.f, wB = 0.f;
      unsigned int cu = mu; int ci = mi;
      #pragma unroll
      for (int k = 0; k < K1B; ++k){
        if (k < ncb && cnt2 < need + 8){
          unsigned int bu = cu; int bi = ci;
          #pragma unroll
          for (int off=32; off; off>>=1){
            unsigned int ou = __shfl_xor(bu, off); int oi = __shfl_xor(bi, off);
            if (ou > bu || (ou == bu && oi < bi)){ bu = ou; bi = oi; }
          }
          if (ci == bi){ cu = 0u; ci = 0x7fffffff; }
          bool mem = false;
          #pragma unroll
          for (int j=0;j<ESIM;j++) if (ssel[j] == bi) mem = true;
          if (!mem){
            if (lane == 0) sbot[cnt2] = bi;
            float val = inv_map(bu ^ FLIP);
            if (cnt2 == need-1) wA = val;
            if (cnt2 == need)   wB = val;
            cnt2++;
          }
        }
      }
      int npick = min(need, cnt2);
      bool rb = (cnt2 > need) && (wB - wA < TAU);
      if (!rb){
        if (lane < npick) botidx[(size_t)grow*8 + lane] = sbot[lane];
      } else {
        const float* hq = hb + (size_t)t*DD;
        float rt = rnb[t];
        float4 q0 = *(const float4*)&hq[lane*4];
        float4 q1 = *(const float4*)&hq[lane*4 + 256];
        float ev = POS_INF; int ei = 0x7fffffff;
        for (int j = 0; j < cnt2; ++j){
          int idx = sbot[j];
          const float* hc = hb + (size_t)idx*DD;
          float4 c0 = *(const float4*)&hc[lane*4];
          float4 c1 = *(const float4*)&hc[lane*4 + 256];
          float pp = q0.x*c0.x+q0.y*c0.y+q0.z*c0.z+q0.w*c0.w
                   + q1.x*c1.x+q1.y*c1.y+q1.z*c1.z+q1.w*c1.w;
          #pragma unroll
          for (int off=32; off; off>>=1) pp += __shfl_xor(pp, off);
          float ex = pp * rt * rnb[idx];
          if (lane == j){ ev = ex; ei = idx; }
        }
        #pragma unroll
        for (int k = 0; k < ECON; ++k){
          if (k < npick){
            float bv = ev; int bi = ei;
            #pragma unroll
            for (int off=32; off; off>>=1){
              float ov = __shfl_xor(bv, off); int oi = __shfl_xor(bi, off);
              if (ov < bv || (ov == bv && oi < bi)){ bv = ov; bi = oi; }
            }
            if (lane == 0) botidx[(size_t)grow*8 + k] = bi;
            if (ei == bi) ev = POS_INF;
          }
        }
      }
      cnt2 = npick;
    }
    if (lane == 0) bcnt[grow] = cnt2;
  }
}

// ---------------- aggregate + blend + gelu + momentum ----------------
__global__ __launch_bounds__(256) void k_agg(const float* __restrict__ hsrc, float* __restrict__ hdst,
                                             const int* __restrict__ topidx, const int* __restrict__ botidx,
                                             const int* __restrict__ bcnt,
                                             const float* __restrict__ gain, const float* __restrict__ bias,
                                             const float* __restrict__ log_mix, const float* __restrict__ log_alpha,
                                             const float* __restrict__ log_momentum, int r, int eff_sim){
  int row = blockIdx.x;
  int b = row >> 11; int t = row & (TT-1);
  int n_sim = min(eff_sim, t);
  int n_con = bcnt[row];
  float mix      = sigmoidf_(log_mix[r]);
  float alpha    = sigmoidf_(log_alpha[r]);
  float momentum = sigmoidf_(log_momentum[0]);
  const float* hb = hsrc + (size_t)b*TT*DD;

  __shared__ int sidx[16];
  __shared__ int scidx[8];
  if (threadIdx.x < 16) sidx[threadIdx.x]  = (threadIdx.x < n_sim) ? topidx[(size_t)row*16 + threadIdx.x] : 0;
  if (threadIdx.x < 8)  scidx[threadIdx.x] = (threadIdx.x < n_con) ? botidx[(size_t)row*8  + threadIdx.x] : 0;
  __syncthreads();

  #pragma unroll
  for (int e = threadIdx.x; e < DD; e += 256){
    float sp = 0.f;
    for (int j=0;j<n_sim;j++) sp += hb[(size_t)sidx[j]*DD + e];
    float sn = 0.f;
    for (int j=0;j<n_con;j++) sn += hb[(size_t)scidx[j]*DD + e];
    float mp = sp / (float)max(n_sim, 1);
    float mn = sn / (float)max(n_con, 1);
    float ctx = alpha*mp + (1.f-alpha)*mn;
    float hv = hsrc[(size_t)row*DD + e];
    float blended = mix*hv + (1.f-mix)*ctx;
    float u = blended*gain[e] + bias[e];
    float g = 0.5f*u*(1.0f + erff(u*0.7071067811865475f));
    hdst[(size_t)row*DD + e] = momentum*hv + (1.f-momentum)*g;
  }
}

// ---------------- out = (h - x) * scale ----------------
__global__ __launch_bounds__(256) void k_final(const float* __restrict__ hfin, const float* __restrict__ x,
                                               const float* __restrict__ log_scale, float* __restrict__ out, int n){
  float scale = log1pf(expf(log_scale[0])) + 0.01f;
  int i = blockIdx.x*256 + threadIdx.x;
  if (i < n) out[i] = (hfin[i] - x[i]) * scale;
}

extern "C" void kernel_launch(void* const* d_in, const int* in_sizes, int n_in,
                              void* d_out, int out_size, void* d_ws, size_t ws_size,
                              hipStream_t stream) {
  const float* x         = (const float*)d_in[0];
  const float* gain      = (const float*)d_in[1];
  const float* bias      = (const float*)d_in[2];
  const float* log_mix   = (const float*)d_in[3];
  const float* log_alpha = (const float*)d_in[4];
  const float* log_mom   = (const float*)d_in[5];
  const float* log_scale = (const float*)d_in[6];

  float* hA = (float*)d_out;
  char* ws = (char*)d_ws;
  size_t off = 0;
  auto alloc = [&](size_t bytes){ void* p = ws + off; off += (bytes + 255) & ~(size_t)255; return p; };

  float*          hB     = (float*)alloc((size_t)BB*TT*DD*4);
  float*          rnorm  = (float*)alloc((size_t)BB*TT*4);
  int*            topidx = (int*)  alloc((size_t)BB*TT*16*4);
  int*            botidx = (int*)  alloc((size_t)BB*TT*8*4);
  int*            bcnt   = (int*)  alloc((size_t)BB*TT*4);
  unsigned short* Xh     = (unsigned short*)alloc((size_t)BB*TT*DD*2);
  unsigned short* Xl     = (unsigned short*)alloc((size_t)BB*TT*DD*2);

  size_t rem = (ws_size > off) ? (ws_size - off) : 0;
  int cb = (int)(rem / ((size_t)TT*TT*4));
  if (cb < 1) cb = 1;
  if (cb > BB) cb = BB;
  float* sim = (float*)alloc((size_t)cb*TT*TT*4);

  const float* hsrc = x;
  float* hdst = hB;
  const int ks[3] = {4, 8, 16};

  for (int r = 0; r < 3; ++r){
    k_normsplit<<<BB*TT, 64, 0, stream>>>(hsrc, rnorm, Xh, Xl);
    for (int b0 = 0; b0 < BB; b0 += cb){
      int nb = (BB - b0 < cb) ? (BB - b0) : cb;
      dim3 g(136, nb);
      k_sim<<<g, 256, 0, stream>>>(Xh, Xl, sim, b0);
      int rq = nb*TT/4;
      if (r == 0)      k_topk<4,2><<<nb*TT/16, 256, 0, stream>>>(sim, b0, hsrc, rnorm, topidx, botidx, bcnt, rq);
      else if (r == 1) k_topk<8,4><<<nb*TT/16, 256, 0, stream>>>(sim, b0, hsrc, rnorm, topidx, botidx, bcnt, rq);
      else             k_topk<16,8><<<nb*TT/16, 256, 0, stream>>>(sim, b0, hsrc, rnorm, topidx, botidx, bcnt, rq);
    }
    k_agg<<<BB*TT, 256, 0, stream>>>(hsrc, hdst, topidx, botidx, bcnt,
                                     gain + (size_t)r*DD, bias + (size_t)r*DD,
                                     log_mix, log_alpha, log_mom, r, ks[r]);
    if (r == 0){ hsrc = hB; hdst = hA; }
    else if (r == 1){ hsrc = hA; hdst = hB; }
  }
  k_final<<<(BB*TT*DD)/256, 256, 0, stream>>>(hB, x, log_scale, (float*)d_out, BB*TT*DD);
}

// Round 20
// 454.009 us; speedup vs baseline: 8.9382x; 1.6335x over previous
//
#include <hip/hip_runtime.h>
#include <hip/hip_bf16.h>
#include <cstdint>
#include <cstddef>

#define BB 4
#define TT 2048
#define DD 512
#define NEG_INF (-3.402823466e+38f)
#define POS_INF (3.402823466e+38f)

typedef __attribute__((ext_vector_type(8))) short bf16x8;
typedef __attribute__((ext_vector_type(8))) unsigned short ushort8;
typedef __attribute__((ext_vector_type(4))) float f32x4;

__device__ __forceinline__ float sigmoidf_(float x){ return 1.0f/(1.0f+expf(-x)); }

__device__ __forceinline__ unsigned short f2bf(float x){
  __hip_bfloat16 b = __float2bfloat16(x);
  return *reinterpret_cast<unsigned short*>(&b);
}

// monotonic float<->uint map (no NaNs in sim values)
__device__ __forceinline__ unsigned int fwd_map(float f){
  unsigned int b = __float_as_uint(f);
  return b ^ ((b & 0x80000000u) ? 0xFFFFFFFFu : 0x80000000u);
}
__device__ __forceinline__ float inv_map(unsigned int u){
  unsigned int b = (u & 0x80000000u) ? (u ^ 0x80000000u) : ~u;
  return __uint_as_float(b);
}

__device__ __forceinline__ unsigned long long shfl_xor64(unsigned long long x, int off){
  unsigned int hi = __shfl_xor((unsigned int)(x >> 32), off);
  unsigned int lo = __shfl_xor((unsigned int)x, off);
  return ((unsigned long long)hi << 32) | lo;
}

// async global->LDS, 16 bytes per lane; lds dest = wave-uniform base + lane*16
__device__ __forceinline__ void gl_lds16(const unsigned short* g, short* l){
  __builtin_amdgcn_global_load_lds(
    (const __attribute__((address_space(1))) unsigned int*)g,
    (__attribute__((address_space(3))) unsigned int*)l, 16, 0, 0);
}

// ---------------- rnorm + bf16 hi/lo split of xn ----------------
__global__ __launch_bounds__(64) void k_normsplit(const float* __restrict__ h, float* __restrict__ rnorm,
                                                  unsigned short* __restrict__ Xh, unsigned short* __restrict__ Xl){
  int row = blockIdx.x;
  const float* hr = h + (size_t)row*DD;
  int lane = threadIdx.x;
  float4 v0 = *(const float4*)&hr[lane*4];
  float4 v1 = *(const float4*)&hr[lane*4 + 256];
  float ss = v0.x*v0.x+v0.y*v0.y+v0.z*v0.z+v0.w*v0.w
           + v1.x*v1.x+v1.y*v1.y+v1.z*v1.z+v1.w*v1.w;
  #pragma unroll
  for (int off=32; off; off>>=1) ss += __shfl_xor(ss, off);
  float rn = 1.0f / fmaxf(sqrtf(ss), 1e-12f);
  if (lane==0) rnorm[row] = rn;

  float xs[8] = {v0.x,v0.y,v0.z,v0.w,v1.x,v1.y,v1.z,v1.w};
  unsigned short hb[8], lb[8];
  #pragma unroll
  for (int q=0;q<8;q++){
    float xn = xs[q]*rn;
    unsigned short hh = f2bf(xn);
    __hip_bfloat16 bh = *reinterpret_cast<__hip_bfloat16*>(&hh);
    float rem = xn - __bfloat162float(bh);
    hb[q] = hh; lb[q] = f2bf(rem);
  }
  ushort4 h0 = {hb[0],hb[1],hb[2],hb[3]}, h1 = {hb[4],hb[5],hb[6],hb[7]};
  ushort4 l0 = {lb[0],lb[1],lb[2],lb[3]}, l1 = {lb[4],lb[5],lb[6],lb[7]};
  *(ushort4*)&Xh[(size_t)row*DD + lane*4]       = h0;
  *(ushort4*)&Xh[(size_t)row*DD + lane*4 + 256] = h1;
  *(ushort4*)&Xl[(size_t)row*DD + lane*4]       = l0;
  *(ushort4*)&Xl[(size_t)row*DD + lane*4 + 256] = l1;
}

// ---------------- sim via MFMA bf16 3-pass split, 128x128 tile, 8 waves, gload_lds dbuf ----------------
__global__ __launch_bounds__(512) void k_sim(const unsigned short* __restrict__ Xh,
                                             const unsigned short* __restrict__ Xl,
                                             float* __restrict__ sim, int b0){
  int p = blockIdx.x;
  int jt = (int)((sqrtf(8.0f*(float)p + 1.0f) - 1.0f)*0.5f);
  while ((jt+1)*(jt+2)/2 <= p) jt++;
  while (jt*(jt+1)/2 > p) jt--;
  int is = p - jt*(jt+1)/2;

  int bl = blockIdx.y;
  size_t xoff = (size_t)(b0 + bl)*TT*DD;
  const unsigned short* XhB = Xh + xoff;
  const unsigned short* XlB = Xl + xoff;
  float* simb = sim + (size_t)bl*TT*TT;
  int t0 = jt*128, s0 = is*128;

  __shared__ __align__(16) short As[2][4096];   // [buf][128 rows x 32 cols]
  __shared__ __align__(16) short Bs[2][4096];

  int tid = threadIdx.x, wave = tid>>6, lane = tid&63;
  int wr = wave>>2, wc = wave&3;                // 2 x 4 wave grid; each wave: 64x32 output

  int srow = tid>>2;            // 0..127
  int sc8  = (tid&3)*8;         // 0,8,16,24

  size_t offA = (size_t)(t0 + srow)*DD + sc8;
  size_t offB = (size_t)(s0 + srow)*DD + sc8;

  f32x4 acc[4][2];
  #pragma unroll
  for (int m=0;m<4;m++)
    #pragma unroll
    for (int n=0;n<2;n++) acc[m][n] = (f32x4){0.f,0.f,0.f,0.f};

  auto stage = [&](int s, int buf){
    int pass = s>>4; int kcol = (s&15)*32;
    const unsigned short* sA = (pass<2) ? XhB : XlB;
    const unsigned short* sB = (pass!=1) ? XhB : XlB;
    gl_lds16(sA + offA + kcol, &As[buf][wave*512]);
    gl_lds16(sB + offB + kcol, &Bs[buf][wave*512]);
  };

  stage(0, 0);
  __syncthreads();

  int arow = wr*64 + (lane&15);
  int brow = wc*32 + (lane&15);
  int kb = (lane>>4)*8;

  for (int s=0; s<48; ++s){
    int cur = s & 1;
    if (s < 47) stage(s+1, cur^1);
    bf16x8 af[4], bf[2];
    #pragma unroll
    for (int m=0;m<4;m++) af[m] = *(const bf16x8*)&As[cur][(arow + m*16)*32 + kb];
    #pragma unroll
    for (int n=0;n<2;n++) bf[n] = *(const bf16x8*)&Bs[cur][(brow + n*16)*32 + kb];
    #pragma unroll
    for (int m=0;m<4;m++)
      #pragma unroll
      for (int n=0;n<2;n++)
        acc[m][n] = __builtin_amdgcn_mfma_f32_16x16x32_bf16(af[m], bf[n], acc[m][n], 0, 0, 0);
    __syncthreads();
  }

  #pragma unroll
  for (int m=0;m<4;m++){
    int t = t0 + wr*64 + m*16 + (lane>>4)*4;
    #pragma unroll
    for (int n=0;n<2;n++){
      int sc = s0 + wc*32 + n*16 + (lane&15);
      float* dst = simb + (size_t)t*TT + sc;
      #pragma unroll
      for (int j=0;j<4;j++) dst[(size_t)j*TT] = acc[m][n][j];
    }
  }
}

// ---------------- top-k: wave-per-row, single-sweep top-4 + certificate; radix fallback ----------------
#define BMASK 0xFFFFFF00u
#define MKKEY(F,S) ((((unsigned long long)fwd_map(F)) << 32) | (unsigned int)(~(S)))
#define INS(KK) do{ unsigned long long a=(KK); \
  if (a > kv3){ \
    if (a > kv0){ unsigned long long tq=kv0; kv0=a; a=tq; } \
    if (a > kv1){ unsigned long long tq=kv1; kv1=a; a=tq; } \
    if (a > kv2){ unsigned long long tq=kv2; kv2=a; a=tq; } \
    kv3=a; } }while(0)

// 3-pass radix: exact 24-bit bucket of the k1-th largest key (key = fwd_map ^ flip); wave-level
__device__ __forceinline__ unsigned int radix24(const float* __restrict__ srow, int t, int k1,
                                                unsigned int flip, int* sh, int lane){
  #pragma unroll
  for (int i=0;i<4;i++) sh[lane + i*64] = 0;
  int t4 = t & ~3;
  for (int s4 = lane*4; s4 < t4; s4 += 256){
    float4 f = *(const float4*)&srow[s4];
    unsigned int u0=fwd_map(f.x)^flip, u1=fwd_map(f.y)^flip, u2=fwd_map(f.z)^flip, u3=fwd_map(f.w)^flip;
    atomicAdd(&sh[u0>>24],1); atomicAdd(&sh[u1>>24],1);
    atomicAdd(&sh[u2>>24],1); atomicAdd(&sh[u3>>24],1);
  }
  for (int s = t4 + lane; s < t; s += 64){
    unsigned int u = fwd_map(srow[s])^flip;
    atomicAdd(&sh[u>>24],1);
  }
  unsigned int pfx = 0u; int kp = k1;
  #pragma unroll
  for (int pass = 0; pass < 3; ++pass){
    int shift = 24 - 8*pass;
    int m4 = sh[4*lane] + sh[4*lane+1] + sh[4*lane+2] + sh[4*lane+3];
    int x = __shfl(m4, 63-lane);
    #pragma unroll
    for (int off = 1; off < 64; off <<= 1){
      int v = __shfl_up(x, off);
      if (lane >= off) x += v;
    }
    int T = __shfl(x, 63-lane);
    int G = T - m4;
    bool hit = (G < kp) && (kp <= T);
    unsigned int npfx = 0u; int nkp = 0;
    if (hit){
      int c = G; int D = 4*lane;
      #pragma unroll
      for (int i = 3; i >= 0; --i){
        int hc = sh[4*lane + i];
        if (kp <= c + hc){ D = 4*lane + i; break; }
        c += hc;
      }
      npfx = pfx | ((unsigned int)D << shift);
      nkp = kp - c;
    }
    unsigned long long hm = __ballot(hit);
    int src = __ffsll(hm) - 1;
    pfx = __shfl(npfx, src);
    kp  = __shfl(nkp, src);
    if (pass == 2) break;

    int nshift = shift - 8;
    unsigned int keep = 0xFFFFFFFFu << shift;
    #pragma unroll
    for (int i=0;i<4;i++) sh[lane + i*64] = 0;
    for (int s4 = lane*4; s4 < t4; s4 += 256){
      float4 f = *(const float4*)&srow[s4];
      unsigned int u0=fwd_map(f.x)^flip, u1=fwd_map(f.y)^flip, u2=fwd_map(f.z)^flip, u3=fwd_map(f.w)^flip;
      if (((u0 ^ pfx) & keep) == 0) atomicAdd(&sh[(u0>>nshift)&255],1);
      if (((u1 ^ pfx) & keep) == 0) atomicAdd(&sh[(u1>>nshift)&255],1);
      if (((u2 ^ pfx) & keep) == 0) atomicAdd(&sh[(u2>>nshift)&255],1);
      if (((u3 ^ pfx) & keep) == 0) atomicAdd(&sh[(u3>>nshift)&255],1);
    }
    for (int s = t4 + lane; s < t; s += 64){
      unsigned int u = fwd_map(srow[s])^flip;
      if (((u ^ pfx) & keep) == 0) atomicAdd(&sh[(u>>nshift)&255],1);
    }
  }
  return pfx;   // low 8 bits zero
}

template<int ESIM, int ECON>
__global__ __launch_bounds__(256) void k_topk(const float* __restrict__ sim, int b0,
                                              const float* __restrict__ h, const float* __restrict__ rnorm,
                                              int* __restrict__ topidx, int* __restrict__ botidx,
                                              int* __restrict__ bcnt){
  constexpr int K1  = ESIM + 8;
  constexpr int K1B = ESIM + ECON + 8;       // <= 32
  constexpr int CANDCAP = 40;
  constexpr int EQCAP = 44;
  constexpr float TAU = 5e-5f;
  __shared__ int s_hist[4][256];
  __shared__ int s_cand[4][CANDCAP];
  __shared__ int s_eq[4][EQCAP];
  __shared__ int s_sel[4][ESIM];
  __shared__ int s_bot[4][16];
  __shared__ int s_cnt[4][2];

  int tid = threadIdx.x, lane = tid & 63, wid = tid >> 6;
  int lrow = blockIdx.x*4 + wid;
  int bl = lrow >> 11, t = lrow & (TT-1);
  int gb = b0 + bl;
  int grow = (gb << 11) | t;

  if (t <= ESIM){
    if (lane < t) topidx[(size_t)grow*16 + lane] = lane;
    if (lane == 0) bcnt[grow] = 0;
    return;
  }
  const float* srow = sim + (size_t)lrow*TT;
  const float* hb  = h + (size_t)gb*TT*DD;
  const float* rnb = rnorm + (size_t)gb*TT;

  int* sh    = s_hist[wid];
  int* scand = s_cand[wid];
  int* seq   = s_eq[wid];
  int* ssel  = s_sel[wid];
  int* sbot  = s_bot[wid];
  int t4 = t & ~3;

  // ========== FAST TOP PATH: single sweep, per-lane top-4, 4x-unrolled loads ==========
  unsigned long long kv0=0, kv1=0, kv2=0, kv3=0;
  {
    int s4 = lane*4;
    for (; s4 + 772 <= t4; s4 += 1024){
      float4 f0 = *(const float4*)&srow[s4];
      float4 f1 = *(const float4*)&srow[s4+256];
      float4 f2 = *(const float4*)&srow[s4+512];
      float4 f3 = *(const float4*)&srow[s4+768];
      INS(MKKEY(f0.x,s4));     INS(MKKEY(f0.y,s4+1));   INS(MKKEY(f0.z,s4+2));   INS(MKKEY(f0.w,s4+3));
      INS(MKKEY(f1.x,s4+256)); INS(MKKEY(f1.y,s4+257)); INS(MKKEY(f1.z,s4+258)); INS(MKKEY(f1.w,s4+259));
      INS(MKKEY(f2.x,s4+512)); INS(MKKEY(f2.y,s4+513)); INS(MKKEY(f2.z,s4+514)); INS(MKKEY(f2.w,s4+515));
      INS(MKKEY(f3.x,s4+768)); INS(MKKEY(f3.y,s4+769)); INS(MKKEY(f3.z,s4+770)); INS(MKKEY(f3.w,s4+771));
    }
    for (; s4 < t4; s4 += 256){
      float4 f = *(const float4*)&srow[s4];
      INS(MKKEY(f.x,s4)); INS(MKKEY(f.y,s4+1)); INS(MKKEY(f.z,s4+2)); INS(MKKEY(f.w,s4+3));
    }
    for (int s = t4 + lane; s < t; s += 64) INS(MKKEY(srow[s],s));
  }

  // certificate: kv3 bounds (strictly above) every key this lane ever discarded
  unsigned long long cert = kv3;
  #pragma unroll
  for (int off=32; off; off>>=1){
    unsigned long long oc = shfl_xor64(cert, off);
    if (oc > cert) cert = oc;
  }

  int myidx = 0x7fffffff;             // lane k holds the k-th pop's index
  float vA = 0.f, vB = 0.f;
  unsigned long long keyLast = 0ull;
  #pragma unroll
  for (int k = 0; k <= ESIM; ++k){
    unsigned long long bk = kv0;
    #pragma unroll
    for (int off=32; off; off>>=1){
      unsigned long long ok = shfl_xor64(bk, off);
      if (ok > bk) bk = ok;
    }
    if (kv0 == bk){ kv0=kv1; kv1=kv2; kv2=kv3; kv3=0ull; }
    if (lane == k) myidx = (int)(~(unsigned int)bk);
    if (k == ESIM-1) vA = inv_map((unsigned int)(bk >> 32));
    if (k == ESIM){ vB = inv_map((unsigned int)(bk >> 32)); keyLast = bk; }
  }

  // exactness: if cert <= keyLast, no discarded key can be in the top-(ESIM+1) -> pops exact
  bool fb = (cert > keyLast) || (vA - vB < TAU);
  if (!fb){
    if (lane < ESIM){
      ssel[lane] = myidx;
      topidx[(size_t)grow*16 + lane] = myidx;
    }
  } else {
    // ========== FALLBACK: radix24 + collect + extract + gap/rescore ==========
    int k1 = min(t, K1);
    unsigned int thr = radix24(srow, t, k1, 0u, sh, lane);

    if (lane == 0){ s_cnt[wid][0] = 0; s_cnt[wid][1] = 0; }
    for (int s4 = lane*4; s4 < t4; s4 += 256){
      float4 f = *(const float4*)&srow[s4];
      unsigned int uu[4] = {fwd_map(f.x), fwd_map(f.y), fwd_map(f.z), fwd_map(f.w)};
      #pragma unroll
      for (int q=0;q<4;q++){
        unsigned int b24 = uu[q] & BMASK;
        if (b24 > thr){ int p = atomicAdd(&s_cnt[wid][0],1); if (p < CANDCAP) scand[p] = s4+q; }
        else if (b24 == thr){ int p = atomicAdd(&s_cnt[wid][1],1); if (p < EQCAP) seq[p] = s4+q; }
      }
    }
    for (int s = t4 + lane; s < t; s += 64){
      unsigned int b24 = fwd_map(srow[s]) & BMASK;
      if (b24 > thr){ int p = atomicAdd(&s_cnt[wid][0],1); if (p < CANDCAP) scand[p] = s; }
      else if (b24 == thr){ int p = atomicAdd(&s_cnt[wid][1],1); if (p < EQCAP) seq[p] = s; }
    }
    int c_gt = min(s_cnt[wid][0], CANDCAP);
    int c_eq = min(s_cnt[wid][1], EQCAP);
    int ncand = min(c_gt + c_eq, 64);

    unsigned int myu = 0u; int myi = 0x7fffffff;
    if (lane < ncand){
      myi = (lane < c_gt) ? scand[lane] : seq[lane - c_gt];
      myu = fwd_map(srow[myi]);
    }

    float fvA = 0.f, fvB = 0.f;
    {
      unsigned int cu = myu; int ci = myi;
      #pragma unroll
      for (int k = 0; k <= ESIM; ++k){
        unsigned int bu = cu; int bi = ci;
        #pragma unroll
        for (int off=32; off; off>>=1){
          unsigned int ou = __shfl_xor(bu, off); int oi = __shfl_xor(bi, off);
          if (ou > bu || (ou == bu && oi < bi)){ bu = ou; bi = oi; }
        }
        if (k < ESIM && lane == 0) ssel[k] = bi;
        if (k == ESIM-1) fvA = inv_map(bu);
        if (k == ESIM)   fvB = inv_map(bu);
        if (ci == bi){ cu = 0u; ci = 0x7fffffff; }
      }
    }

    bool resc = (fvA - fvB < TAU);
    if (resc){
      const float* hq = hb + (size_t)t*DD;
      float rt = rnb[t];
      float4 q0 = *(const float4*)&hq[lane*4];
      float4 q1 = *(const float4*)&hq[lane*4 + 256];
      float ev = NEG_INF;
      for (int j = 0; j < ncand; ++j){
        int idx = (j < c_gt) ? scand[j] : seq[j - c_gt];
        const float* hc = hb + (size_t)idx*DD;
        float4 c0 = *(const float4*)&hc[lane*4];
        float4 c1 = *(const float4*)&hc[lane*4 + 256];
        float pp = q0.x*c0.x+q0.y*c0.y+q0.z*c0.z+q0.w*c0.w
                 + q1.x*c1.x+q1.y*c1.y+q1.z*c1.z+q1.w*c1.w;
        #pragma unroll
        for (int off=32; off; off>>=1) pp += __shfl_xor(pp, off);
        float ex = pp * rt * rnb[idx];
        if (lane == j) ev = ex;
      }
      float rv = (lane < ncand) ? ev : NEG_INF;
      int   ri = myi;
      #pragma unroll
      for (int k = 0; k < ESIM; ++k){
        float bv = rv; int bi = ri;
        #pragma unroll
        for (int off=32; off; off>>=1){
          float ov = __shfl_xor(bv, off); int oi = __shfl_xor(bi, off);
          if (ov > bv || (ov == bv && oi < bi)){ bv = ov; bi = oi; }
        }
        if (lane == 0) ssel[k] = bi;
        if (ri == bi) rv = NEG_INF;
      }
    }
    if (lane < ESIM) topidx[(size_t)grow*16 + lane] = ssel[lane];
  }

  // ---------- BOTTOM path (rows with t > TT-ECON only, <=7 per batch) ----------
  int need = ECON - (TT - t);
  int cnt2 = 0;
  if (need > 0){
    constexpr unsigned int FLIP = 0xFFFFFFFFu;
    int k1b = min(t, K1B);
    unsigned int thrb = radix24(srow, t, k1b, FLIP, sh, lane);

    if (lane == 0){ s_cnt[wid][0] = 0; s_cnt[wid][1] = 0; }
    for (int s4 = lane*4; s4 < t4; s4 += 256){
      float4 f = *(const float4*)&srow[s4];
      unsigned int uu[4] = {fwd_map(f.x)^FLIP, fwd_map(f.y)^FLIP, fwd_map(f.z)^FLIP, fwd_map(f.w)^FLIP};
      #pragma unroll
      for (int q=0;q<4;q++){
        unsigned int b24 = uu[q] & BMASK;
        if (b24 > thrb){ int p = atomicAdd(&s_cnt[wid][0],1); if (p < CANDCAP) scand[p] = s4+q; }
        else if (b24 == thrb){ int p = atomicAdd(&s_cnt[wid][1],1); if (p < EQCAP) seq[p] = s4+q; }
      }
    }
    for (int s = t4 + lane; s < t; s += 64){
      unsigned int u = fwd_map(srow[s])^FLIP;
      unsigned int b24 = u & BMASK;
      if (b24 > thrb){ int p = atomicAdd(&s_cnt[wid][0],1); if (p < CANDCAP) scand[p] = s; }
      else if (b24 == thrb){ int p = atomicAdd(&s_cnt[wid][1],1); if (p < EQCAP) seq[p] = s; }
    }
    int bc_gt = min(s_cnt[wid][0], CANDCAP);
    int bc_eq = min(s_cnt[wid][1], EQCAP);
    int ncb = min(bc_gt + bc_eq, 64);

    unsigned int mu = 0u; int mi = 0x7fffffff;
    if (lane < ncb){
      mi = (lane < bc_gt) ? scand[lane] : seq[lane - bc_gt];
      mu = fwd_map(srow[mi]) ^ FLIP;
    }
    float wA = 0.f, wB = 0.f;
    unsigned int cu = mu; int ci = mi;
    #pragma unroll
    for (int k = 0; k < K1B; ++k){
      if (k < ncb && cnt2 < need + 8){
        unsigned int bu = cu; int bi = ci;
        #pragma unroll
        for (int off=32; off; off>>=1){
          unsigned int ou = __shfl_xor(bu, off); int oi = __shfl_xor(bi, off);
          if (ou > bu || (ou == bu && oi < bi)){ bu = ou; bi = oi; }
        }
        if (ci == bi){ cu = 0u; ci = 0x7fffffff; }
        bool mem = false;
        #pragma unroll
        for (int j=0;j<ESIM;j++) if (ssel[j] == bi) mem = true;
        if (!mem){
          if (lane == 0) sbot[cnt2] = bi;
          float val = inv_map(bu ^ FLIP);
          if (cnt2 == need-1) wA = val;
          if (cnt2 == need)   wB = val;
          cnt2++;
        }
      }
    }
    int npick = min(need, cnt2);
    bool rb = (cnt2 > need) && (wB - wA < TAU);
    if (!rb){
      if (lane < npick) botidx[(size_t)grow*8 + lane] = sbot[lane];
    } else {
      const float* hq = hb + (size_t)t*DD;
      float rt = rnb[t];
      float4 q0 = *(const float4*)&hq[lane*4];
      float4 q1 = *(const float4*)&hq[lane*4 + 256];
      float ev = POS_INF; int ei = 0x7fffffff;
      for (int j = 0; j < cnt2; ++j){
        int idx = sbot[j];
        const float* hc = hb + (size_t)idx*DD;
        float4 c0 = *(const float4*)&hc[lane*4];
        float4 c1 = *(const float4*)&hc[lane*4 + 256];
        float pp = q0.x*c0.x+q0.y*c0.y+q0.z*c0.z+q0.w*c0.w
                 + q1.x*c1.x+q1.y*c1.y+q1.z*c1.z+q1.w*c1.w;
        #pragma unroll
        for (int off=32; off; off>>=1) pp += __shfl_xor(pp, off);
        float ex = pp * rt * rnb[idx];
        if (lane == j){ ev = ex; ei = idx; }
      }
      #pragma unroll
      for (int k = 0; k < ECON; ++k){
        if (k < npick){
          float bv = ev; int bi = ei;
          #pragma unroll
          for (int off=32; off; off>>=1){
            float ov = __shfl_xor(bv, off); int oi = __shfl_xor(bi, off);
            if (ov < bv || (ov == bv && oi < bi)){ bv = ov; bi = oi; }
          }
          if (lane == 0) botidx[(size_t)grow*8 + k] = bi;
          if (ei == bi) ev = POS_INF;
        }
      }
    }
    cnt2 = npick;
  }
  if (lane == 0) bcnt[grow] = cnt2;
}

// ---------------- aggregate + blend + gelu + momentum ----------------
__global__ __launch_bounds__(256) void k_agg(const float* __restrict__ hsrc, float* __restrict__ hdst,
                                             const int* __restrict__ topidx, const int* __restrict__ botidx,
                                             const int* __restrict__ bcnt,
                                             const float* __restrict__ gain, const float* __restrict__ bias,
                                             const float* __restrict__ log_mix, const float* __restrict__ log_alpha,
                                             const float* __restrict__ log_momentum, int r, int eff_sim){
  int row = blockIdx.x;
  int b = row >> 11; int t = row & (TT-1);
  int n_sim = min(eff_sim, t);
  int n_con = bcnt[row];
  float mix      = sigmoidf_(log_mix[r]);
  float alpha    = sigmoidf_(log_alpha[r]);
  float momentum = sigmoidf_(log_momentum[0]);
  const float* hb = hsrc + (size_t)b*TT*DD;

  __shared__ int sidx[16];
  __shared__ int scidx[8];
  if (threadIdx.x < 16) sidx[threadIdx.x]  = (threadIdx.x < n_sim) ? topidx[(size_t)row*16 + threadIdx.x] : 0;
  if (threadIdx.x < 8)  scidx[threadIdx.x] = (threadIdx.x < n_con) ? botidx[(size_t)row*8  + threadIdx.x] : 0;
  __syncthreads();

  #pragma unroll
  for (int e = threadIdx.x; e < DD; e += 256){
    float sp = 0.f;
    for (int j=0;j<n_sim;j++) sp += hb[(size_t)sidx[j]*DD + e];
    float sn = 0.f;
    for (int j=0;j<n_con;j++) sn += hb[(size_t)scidx[j]*DD + e];
    float mp = sp / (float)max(n_sim, 1);
    float mn = sn / (float)max(n_con, 1);
    float ctx = alpha*mp + (1.f-alpha)*mn;
    float hv = hsrc[(size_t)row*DD + e];
    float blended = mix*hv + (1.f-mix)*ctx;
    float u = blended*gain[e] + bias[e];
    float g = 0.5f*u*(1.0f + erff(u*0.7071067811865475f));
    hdst[(size_t)row*DD + e] = momentum*hv + (1.f-momentum)*g;
  }
}

// ---------------- out = (h - x) * scale ----------------
__global__ __launch_bounds__(256) void k_final(const float* __restrict__ hfin, const float* __restrict__ x,
                                               const float* __restrict__ log_scale, float* __restrict__ out, int n){
  float scale = log1pf(expf(log_scale[0])) + 0.01f;
  int i = blockIdx.x*256 + threadIdx.x;
  if (i < n) out[i] = (hfin[i] - x[i]) * scale;
}

extern "C" void kernel_launch(void* const* d_in, const int* in_sizes, int n_in,
                              void* d_out, int out_size, void* d_ws, size_t ws_size,
                              hipStream_t stream) {
  const float* x         = (const float*)d_in[0];
  const float* gain      = (const float*)d_in[1];
  const float* bias      = (const float*)d_in[2];
  const float* log_mix   = (const float*)d_in[3];
  const float* log_alpha = (const float*)d_in[4];
  const float* log_mom   = (const float*)d_in[5];
  const float* log_scale = (const float*)d_in[6];

  float* hA = (float*)d_out;
  char* ws = (char*)d_ws;
  size_t off = 0;
  auto alloc = [&](size_t bytes){ void* p = ws + off; off += (bytes + 255) & ~(size_t)255; return p; };

  float*          hB     = (float*)alloc((size_t)BB*TT*DD*4);
  float*          rnorm  = (float*)alloc((size_t)BB*TT*4);
  int*            topidx = (int*)  alloc((size_t)BB*TT*16*4);
  int*            botidx = (int*)  alloc((size_t)BB*TT*8*4);
  int*            bcnt   = (int*)  alloc((size_t)BB*TT*4);
  unsigned short* Xh     = (unsigned short*)alloc((size_t)BB*TT*DD*2);
  unsigned short* Xl     = (unsigned short*)alloc((size_t)BB*TT*DD*2);

  size_t rem = (ws_size > off) ? (ws_size - off) : 0;
  int cb = (int)(rem / ((size_t)TT*TT*4));
  if (cb < 1) cb = 1;
  if (cb > BB) cb = BB;
  float* sim = (float*)alloc((size_t)cb*TT*TT*4);

  const float* hsrc = x;
  float* hdst = hB;
  const int ks[3] = {4, 8, 16};

  for (int r = 0; r < 3; ++r){
    k_normsplit<<<BB*TT, 64, 0, stream>>>(hsrc, rnorm, Xh, Xl);
    for (int b0 = 0; b0 < BB; b0 += cb){
      int nb = (BB - b0 < cb) ? (BB - b0) : cb;
      dim3 g(136, nb);
      k_sim<<<g, 512, 0, stream>>>(Xh, Xl, sim, b0);
      if (r == 0)      k_topk<4,2><<<nb*TT/4, 256, 0, stream>>>(sim, b0, hsrc, rnorm, topidx, botidx, bcnt);
      else if (r == 1) k_topk<8,4><<<nb*TT/4, 256, 0, stream>>>(sim, b0, hsrc, rnorm, topidx, botidx, bcnt);
      else             k_topk<16,8><<<nb*TT/4, 256, 0, stream>>>(sim, b0, hsrc, rnorm, topidx, botidx, bcnt);
    }
    k_agg<<<BB*TT, 256, 0, stream>>>(hsrc, hdst, topidx, botidx, bcnt,
                                     gain + (size_t)r*DD, bias + (size_t)r*DD,
                                     log_mix, log_alpha, log_mom, r, ks[r]);
    if (r == 0){ hsrc = hB; hdst = hA; }
    else if (r == 1){ hsrc = hA; hdst = hB; }
  }
  k_final<<<(BB*TT*DD)/256, 256, 0, stream>>>(hB, x, log_scale, (float*)d_out, BB*TT*DD);
}